// Round 10
// baseline (664.836 us; speedup 1.0000x reference)
//
#include <hip/hip_runtime.h>
#include <hip/hip_bf16.h>

#define N_NODES   100000
#define N_EDGES   1600000
#define DIM       64
#define OUT_DIM   10
#define N_GRAPHS  1000
#define BN_EPS    1e-5f
#define NBUCKET   391          // ceil(N_NODES / 256)
#define TILE_E    8192
#define NT        196          // ceil(N_EDGES / TILE_E)

typedef __hip_bfloat16 bf16;
__device__ __forceinline__ float b2f(bf16 v) { return __bfloat162float(v); }

// ---- phase 1: per-tile bucket histogram (LDS atomics only) ----

__global__ void __launch_bounds__(256) k_bucket_count(const int* __restrict__ dst,
                                                      int* __restrict__ tileCnt, int e) {
    __shared__ int hcnt[NBUCKET];
    int t = blockIdx.x, tid = threadIdx.x;
    for (int b = tid; b < NBUCKET; b += 256) hcnt[b] = 0;
    __syncthreads();
    int ibase = t * TILE_E;
    for (int j = 0; j < TILE_E; j += 256) {
        int i = ibase + j + tid;
        if (i < e) atomicAdd(&hcnt[dst[i] >> 8], 1);
    }
    __syncthreads();
    for (int b = tid; b < NBUCKET; b += 256) tileCnt[b * NT + t] = hcnt[b];
}

// ---- phase 2a: per-bucket exclusive scan over tiles (in-place) + bucket totals ----

__global__ void __launch_bounds__(256) k_tile_scan(int* __restrict__ tileCnt,
                                                   int* __restrict__ bucketTot) {
    __shared__ int tmp[256];
    int b = blockIdx.x, tid = threadIdx.x;
    int v = (tid < NT) ? tileCnt[b * NT + tid] : 0;
    tmp[tid] = v;
    __syncthreads();
    for (int off = 1; off < 256; off <<= 1) {
        int t = (tid >= off) ? tmp[tid - off] : 0;
        __syncthreads();
        tmp[tid] += t;
        __syncthreads();
    }
    if (tid < NT) tileCnt[b * NT + tid] = tmp[tid] - v;   // exclusive over tiles
    if (tid == 255) bucketTot[b] = tmp[255];
}

// ---- phase 2b: single-block exclusive scan of bucket totals (nb <= 512) ----

__global__ void k_scan_sums(int* __restrict__ bsums, int nb) {
    __shared__ int tmp[512];
    int tid = threadIdx.x;
    int v = (tid < nb) ? bsums[tid] : 0;
    tmp[tid] = v;
    __syncthreads();
    for (int off = 1; off < 512; off <<= 1) {
        int t = (tid >= off) ? tmp[tid - off] : 0;
        __syncthreads();
        tmp[tid] += t;
        __syncthreads();
    }
    if (tid < nb) bsums[tid] = tmp[tid] - v;      // exclusive -> bucket base
}

// ---- phase 3: write edges into per-tile reserved ranges (dense, no global atomics) ----

__global__ void __launch_bounds__(256) k_bucket_write(
    const int* __restrict__ src, const int* __restrict__ dst,
    const int* __restrict__ bbase, const int* __restrict__ tilePrefix,
    unsigned int* __restrict__ packed, int e) {
    __shared__ int hbase[NBUCKET];
    __shared__ int hcur[NBUCKET];
    int t = blockIdx.x, tid = threadIdx.x;
    for (int b = tid; b < NBUCKET; b += 256) {
        hbase[b] = bbase[b] + tilePrefix[b * NT + t];
        hcur[b] = 0;
    }
    __syncthreads();
    int ibase = t * TILE_E;
    for (int j = 0; j < TILE_E; j += 256) {
        int i = ibase + j + tid;
        if (i < e) {
            int d  = dst[i];
            int bb = d >> 8;
            int pos = hbase[bb] + atomicAdd(&hcur[bb], 1);
            packed[pos] = ((unsigned int)src[i] << 8) | (unsigned int)(d & 255);
        }
    }
}

// ---- phase 4: within-bucket counting sort; also emits offs/hist/dinv ----

__global__ void __launch_bounds__(256) k_local_sort(
    const unsigned int* __restrict__ packed, const int* __restrict__ bbase,
    int* __restrict__ ssrc, int* __restrict__ offs, int* __restrict__ hist,
    float* __restrict__ dinv, int n, int e) {
    __shared__ int tmp[256];
    __shared__ int noffs[256];
    __shared__ int ncur[256];
    int b = blockIdx.x, tid = threadIdx.x;
    int base   = b << 8;
    int estart = bbase[b];
    int eend   = (b + 1 < NBUCKET) ? bbase[b + 1] : e;

    ncur[tid] = 0;                 // reuse as per-node counter first
    __syncthreads();
    for (int i = estart + tid; i < eend; i += 256)
        atomicAdd(&ncur[packed[i] & 255u], 1);
    __syncthreads();
    int v = ncur[tid];             // degree of node base+tid
    tmp[tid] = v;
    __syncthreads();
    for (int off = 1; off < 256; off <<= 1) {
        int t = (tid >= off) ? tmp[tid - off] : 0;
        __syncthreads();
        tmp[tid] += t;
        __syncthreads();
    }
    int mystart = estart + tmp[tid] - v;   // exclusive within bucket
    noffs[tid] = mystart;
    ncur[tid]  = 0;
    int node = base + tid;
    if (node < n) {
        offs[node] = mystart;
        hist[node] = v;
        dinv[node] = rsqrtf((float)(v + 1));   // +1 self loop
    }
    __syncthreads();
    for (int i = estart + tid; i < eend; i += 256) {
        unsigned int p = packed[i];
        int d = p & 255u;
        int pos = noffs[d] + atomicAdd(&ncur[d], 1);
        ssrc[pos] = (int)(p >> 8);
    }
}

// ---------------- layer-0 matmul: Hs[n] = dinv[n] * (x[n] @ W) -> bf16 ----------------

__global__ void k_matmul(const float* __restrict__ h, const float* __restrict__ W,
                         const float* __restrict__ dinv, bf16* __restrict__ Hs, int n) {
    int lane = threadIdx.x & 63;
    int wv   = threadIdx.x >> 6;

    float Wreg[64];
#pragma unroll
    for (int k = 0; k < 64; k++) Wreg[k] = W[k * 64 + lane];

    for (int row = blockIdx.x * 4 + wv; row < n; row += gridDim.x * 4) {
        float hval = h[row * 64 + lane];
        float acc = 0.f;
#pragma unroll
        for (int k = 0; k < 64; k++)
            acc = fmaf(__shfl(hval, k, 64), Wreg[k], acc);
        Hs[row * 64 + lane] = __float2bfloat16(dinv[row] * acc);
    }
}

// ------- gather + bias + BN(eval) + relu + JK-pool + fused next-layer matmul -------
// One wave per node. Row = 128B bf16 = 32 lanes x uint (2 bf16/lane).
// Half-waves (sub=lane>>5) process different edges: 8 slots x 2 subs = 16
// edges in flight (R9 was latency-bound at 8: VALUBusy 36%, hbm 18%).
// bf16->f32 via bit ops; lane q holds features 2q/2q+1; single shfl_xor(32)
// reduction, no lane redistribution.

__global__ void __launch_bounds__(256) k_gather(
    const bf16* __restrict__ Hs, const int* __restrict__ ssrc,
    const int* __restrict__ offs, const int* __restrict__ hist,
    const float* __restrict__ dinv, const float* __restrict__ bias,
    const float* __restrict__ gamma, const float* __restrict__ beta,
    const float* __restrict__ mean, const float* __restrict__ var,
    const int* __restrict__ batch, const float* __restrict__ Wnext,
    bf16* __restrict__ HsNext, float* __restrict__ pooled, int layer, int n)
{
    int node = blockIdx.x * 4 + (threadIdx.x >> 6);
    int lane = threadIdx.x & 63;
    if (node >= n) return;
    int q   = lane & 31;
    int sub = lane >> 5;

    int start = __builtin_amdgcn_readfirstlane(offs[node]);
    int cnt   = __builtin_amdgcn_readfirstlane(hist[node]);

    const unsigned int* Hs2 = (const unsigned int*)Hs;

    float accx = 0.f, accy = 0.f;
    if (sub == 0) {                               // self-loop term (pre-scaled)
        unsigned int u = Hs2[node * 32 + q];
        accx = __uint_as_float(u << 16);
        accy = __uint_as_float(u & 0xFFFF0000u);
    }

    int i = 0;
    for (; i + 15 < cnt; i += 16) {
        int s0 = ssrc[start + i      + sub];
        int s1 = ssrc[start + i + 2  + sub];
        int s2 = ssrc[start + i + 4  + sub];
        int s3 = ssrc[start + i + 6  + sub];
        int s4 = ssrc[start + i + 8  + sub];
        int s5 = ssrc[start + i + 10 + sub];
        int s6 = ssrc[start + i + 12 + sub];
        int s7 = ssrc[start + i + 14 + sub];
        unsigned int u0 = Hs2[s0 * 32 + q];
        unsigned int u1 = Hs2[s1 * 32 + q];
        unsigned int u2 = Hs2[s2 * 32 + q];
        unsigned int u3 = Hs2[s3 * 32 + q];
        unsigned int u4 = Hs2[s4 * 32 + q];
        unsigned int u5 = Hs2[s5 * 32 + q];
        unsigned int u6 = Hs2[s6 * 32 + q];
        unsigned int u7 = Hs2[s7 * 32 + q];
        accx += ((__uint_as_float(u0 << 16) + __uint_as_float(u1 << 16)) +
                 (__uint_as_float(u2 << 16) + __uint_as_float(u3 << 16))) +
                ((__uint_as_float(u4 << 16) + __uint_as_float(u5 << 16)) +
                 (__uint_as_float(u6 << 16) + __uint_as_float(u7 << 16)));
        accy += ((__uint_as_float(u0 & 0xFFFF0000u) + __uint_as_float(u1 & 0xFFFF0000u)) +
                 (__uint_as_float(u2 & 0xFFFF0000u) + __uint_as_float(u3 & 0xFFFF0000u))) +
                ((__uint_as_float(u4 & 0xFFFF0000u) + __uint_as_float(u5 & 0xFFFF0000u)) +
                 (__uint_as_float(u6 & 0xFFFF0000u) + __uint_as_float(u7 & 0xFFFF0000u)));
    }
    for (; i + 1 < cnt; i += 2) {
        int s = ssrc[start + i + sub];
        unsigned int u = Hs2[s * 32 + q];
        accx += __uint_as_float(u << 16);
        accy += __uint_as_float(u & 0xFFFF0000u);
    }
    if (i < cnt && sub == 0) {                    // odd last edge: one half only
        int s = ssrc[start + i];
        unsigned int u = Hs2[s * 32 + q];
        accx += __uint_as_float(u << 16);
        accy += __uint_as_float(u & 0xFFFF0000u);
    }

    accx += __shfl_xor(accx, 32, 64);
    accy += __shfl_xor(accy, 32, 64);

    float dn = dinv[node];
    float2 bi = ((const float2*)bias)[q];
    float2 me = ((const float2*)mean)[q];
    float2 va = ((const float2*)var)[q];
    float2 ga = ((const float2*)gamma)[q];
    float2 be = ((const float2*)beta)[q];
    float valx = dn * accx + bi.x;
    valx = (valx - me.x) * (ga.x * rsqrtf(va.x + BN_EPS)) + be.x;
    valx = fmaxf(valx, 0.f);
    float valy = dn * accy + bi.y;
    valy = (valy - me.y) * (ga.y * rsqrtf(va.y + BN_EPS)) + be.y;
    valy = fmaxf(valy, 0.f);

    if (sub == 0) {
        float* pb = &pooled[batch[node] * 256 + layer * 64];
        atomicAdd(&pb[2 * q],     valx);
        atomicAdd(&pb[2 * q + 1], valy);
    }

    if (Wnext) {   // fused next-layer matmul: HsNext[node] = dinv[node]*(val @ Wnext)
        float a2 = 0.f;
#pragma unroll
        for (int m = 0; m < 32; m++) {
            a2 = fmaf(__shfl(valx, m, 64), Wnext[(2 * m) * 64 + lane], a2);
            a2 = fmaf(__shfl(valy, m, 64), Wnext[(2 * m + 1) * 64 + lane], a2);
        }
        HsNext[node * 64 + lane] = __float2bfloat16(dn * a2);
    }
}

// ---------------- final MLP: relu(pooled@W1+b1)@W2+b2 -> f32 out ----------------

__global__ void k_mlp(const float* __restrict__ pooled, const float* __restrict__ W1,
                      const float* __restrict__ b1, const float* __restrict__ W2,
                      const float* __restrict__ b2, float* __restrict__ out) {
    __shared__ float p[256];
    __shared__ float t[64];
    int g = blockIdx.x;
    int tid = threadIdx.x;    // 64 threads
    for (int i = tid; i < 256; i += 64) p[i] = pooled[g * 256 + i];
    __syncthreads();
    float acc = b1[tid];
    for (int k = 0; k < 256; k++)
        acc = fmaf(p[k], W1[k * 64 + tid], acc);
    t[tid] = fmaxf(acc, 0.f);
    __syncthreads();
    if (tid < OUT_DIM) {
        float o = b2[tid];
#pragma unroll
        for (int d = 0; d < 64; d++)
            o = fmaf(t[d], W2[d * OUT_DIM + tid], o);
        out[g * OUT_DIM + tid] = o;
    }
}

// ---------------- host launch ----------------

extern "C" void kernel_launch(void* const* d_in, const int* in_sizes, int n_in,
                              void* d_out, int out_size, void* d_ws, size_t ws_size,
                              hipStream_t stream) {
    const float* x          = (const float*)d_in[0];
    const int*   edge_index = (const int*)d_in[1];
    const int*   batch      = (const int*)d_in[2];
    const float* Wl[4] = { (const float*)d_in[4], (const float*)d_in[6],
                           (const float*)d_in[8], (const float*)d_in[10] };
    const float* bl[4] = { (const float*)d_in[5], (const float*)d_in[7],
                           (const float*)d_in[9], (const float*)d_in[11] };
    const float* bn_gamma = (const float*)d_in[12];
    const float* bn_beta  = (const float*)d_in[13];
    const float* bn_mean  = (const float*)d_in[14];
    const float* bn_var   = (const float*)d_in[15];
    const float* lin1_W = (const float*)d_in[16];
    const float* lin1_b = (const float*)d_in[17];
    const float* lin2_W = (const float*)d_in[18];
    const float* lin2_b = (const float*)d_in[19];

    const int* src = edge_index;             // edge_index[0, :]
    const int* dst = edge_index + N_EDGES;   // edge_index[1, :]

    // ---- workspace bump allocator (~41 MB) ----
    char* p = (char*)d_ws;
    auto alloc = [&](size_t bytes) {
        char* r = p;
        p += (bytes + 255) & ~(size_t)255;
        return (void*)r;
    };
    bf16*  HsA    = (bf16*) alloc((size_t)N_NODES * 64 * 2);
    bf16*  HsB    = (bf16*) alloc((size_t)N_NODES * 64 * 2);
    int*   hist   = (int*)  alloc((size_t)N_NODES * 4);
    int*   offs   = (int*)  alloc((size_t)N_NODES * 4);
    float* dinv   = (float*)alloc((size_t)N_NODES * 4);
    int*   ssrc   = (int*)  alloc((size_t)N_EDGES * 4);
    unsigned int* packed = (unsigned int*)alloc((size_t)N_EDGES * 4);
    int*   tileCnt   = (int*)alloc((size_t)NBUCKET * NT * 4);
    int*   bucketTot = (int*)alloc((size_t)NBUCKET * 4);
    float* pooled = (float*)alloc((size_t)N_GRAPHS * 256 * 4);

    hipMemsetAsync(pooled, 0, (size_t)N_GRAPHS * 256 * 4, stream);

    // deterministic bucketed counting sort (no global atomics anywhere)
    k_bucket_count<<<NT, 256, 0, stream>>>(dst, tileCnt, N_EDGES);
    k_tile_scan<<<NBUCKET, 256, 0, stream>>>(tileCnt, bucketTot);
    k_scan_sums<<<1, 512, 0, stream>>>(bucketTot, NBUCKET);       // -> bucket bases
    k_bucket_write<<<NT, 256, 0, stream>>>(src, dst, bucketTot, tileCnt, packed, N_EDGES);
    k_local_sort<<<NBUCKET, 256, 0, stream>>>(packed, bucketTot, ssrc, offs, hist,
                                              dinv, N_NODES, N_EDGES);

    // layer-0 matmul, then 4 fused gather layers (ping-pong Hs buffers)
    k_matmul<<<2048, 256, 0, stream>>>(x, Wl[0], dinv, HsA, N_NODES);

    const int gatherBlocks = (N_NODES + 3) / 4;  // 4 waves/block, 1 node/wave
    bf16* hsIn[4]  = { HsA, HsB, HsA, HsB };
    bf16* hsOut[4] = { HsB, HsA, HsB, (bf16*)nullptr };
    for (int layer = 0; layer < 4; layer++) {
        const float* wn = (layer < 3) ? Wl[layer + 1] : nullptr;
        k_gather<<<gatherBlocks, 256, 0, stream>>>(
            hsIn[layer], ssrc, offs, hist, dinv, bl[layer],
            bn_gamma + layer * 64, bn_beta + layer * 64,
            bn_mean + layer * 64, bn_var + layer * 64,
            batch, wn, hsOut[layer], pooled, layer, N_NODES);
    }

    k_mlp<<<N_GRAPHS, 64, 0, stream>>>(pooled, lin1_W, lin1_b, lin2_W, lin2_b,
                                       (float*)d_out);
}

// Round 11
// 527.607 us; speedup vs baseline: 1.2601x; 1.2601x over previous
//
#include <hip/hip_runtime.h>
#include <hip/hip_bf16.h>

#define N_NODES   100000
#define N_EDGES   1600000
#define DIM       64
#define OUT_DIM   10
#define N_GRAPHS  1000
#define BN_EPS    1e-5f
#define NBUCKET   391          // ceil(N_NODES / 256)
#define TILE_E    8192
#define NT        196          // ceil(N_EDGES / TILE_E)

typedef __hip_bfloat16 bf16;
__device__ __forceinline__ float b2f(bf16 v) { return __bfloat162float(v); }

// ---- phase 1: per-tile bucket histogram (LDS atomics only) ----

__global__ void __launch_bounds__(256) k_bucket_count(const int* __restrict__ dst,
                                                      int* __restrict__ tileCnt, int e) {
    __shared__ int hcnt[NBUCKET];
    int t = blockIdx.x, tid = threadIdx.x;
    for (int b = tid; b < NBUCKET; b += 256) hcnt[b] = 0;
    __syncthreads();
    int ibase = t * TILE_E;
    for (int j = 0; j < TILE_E; j += 256) {
        int i = ibase + j + tid;
        if (i < e) atomicAdd(&hcnt[dst[i] >> 8], 1);
    }
    __syncthreads();
    for (int b = tid; b < NBUCKET; b += 256) tileCnt[b * NT + t] = hcnt[b];
}

// ---- phase 2a: per-bucket exclusive scan over tiles (in-place) + bucket totals ----

__global__ void __launch_bounds__(256) k_tile_scan(int* __restrict__ tileCnt,
                                                   int* __restrict__ bucketTot) {
    __shared__ int tmp[256];
    int b = blockIdx.x, tid = threadIdx.x;
    int v = (tid < NT) ? tileCnt[b * NT + tid] : 0;
    tmp[tid] = v;
    __syncthreads();
    for (int off = 1; off < 256; off <<= 1) {
        int t = (tid >= off) ? tmp[tid - off] : 0;
        __syncthreads();
        tmp[tid] += t;
        __syncthreads();
    }
    if (tid < NT) tileCnt[b * NT + tid] = tmp[tid] - v;   // exclusive over tiles
    if (tid == 255) bucketTot[b] = tmp[255];
}

// ---- phase 2b: single-block exclusive scan of bucket totals (nb <= 512) ----

__global__ void k_scan_sums(int* __restrict__ bsums, int nb) {
    __shared__ int tmp[512];
    int tid = threadIdx.x;
    int v = (tid < nb) ? bsums[tid] : 0;
    tmp[tid] = v;
    __syncthreads();
    for (int off = 1; off < 512; off <<= 1) {
        int t = (tid >= off) ? tmp[tid - off] : 0;
        __syncthreads();
        tmp[tid] += t;
        __syncthreads();
    }
    if (tid < nb) bsums[tid] = tmp[tid] - v;      // exclusive -> bucket base
}

// ---- phase 3: write edges into per-tile reserved ranges (dense, no global atomics) ----

__global__ void __launch_bounds__(256) k_bucket_write(
    const int* __restrict__ src, const int* __restrict__ dst,
    const int* __restrict__ bbase, const int* __restrict__ tilePrefix,
    unsigned int* __restrict__ packed, int e) {
    __shared__ int hbase[NBUCKET];
    __shared__ int hcur[NBUCKET];
    int t = blockIdx.x, tid = threadIdx.x;
    for (int b = tid; b < NBUCKET; b += 256) {
        hbase[b] = bbase[b] + tilePrefix[b * NT + t];
        hcur[b] = 0;
    }
    __syncthreads();
    int ibase = t * TILE_E;
    for (int j = 0; j < TILE_E; j += 256) {
        int i = ibase + j + tid;
        if (i < e) {
            int d  = dst[i];
            int bb = d >> 8;
            int pos = hbase[bb] + atomicAdd(&hcur[bb], 1);
            packed[pos] = ((unsigned int)src[i] << 8) | (unsigned int)(d & 255);
        }
    }
}

// ---- phase 4: within-bucket counting sort; also emits offs/hist/dinv ----

__global__ void __launch_bounds__(256) k_local_sort(
    const unsigned int* __restrict__ packed, const int* __restrict__ bbase,
    int* __restrict__ ssrc, int* __restrict__ offs, int* __restrict__ hist,
    float* __restrict__ dinv, int n, int e) {
    __shared__ int tmp[256];
    __shared__ int noffs[256];
    __shared__ int ncur[256];
    int b = blockIdx.x, tid = threadIdx.x;
    int base   = b << 8;
    int estart = bbase[b];
    int eend   = (b + 1 < NBUCKET) ? bbase[b + 1] : e;

    ncur[tid] = 0;                 // reuse as per-node counter first
    __syncthreads();
    for (int i = estart + tid; i < eend; i += 256)
        atomicAdd(&ncur[packed[i] & 255u], 1);
    __syncthreads();
    int v = ncur[tid];             // degree of node base+tid
    tmp[tid] = v;
    __syncthreads();
    for (int off = 1; off < 256; off <<= 1) {
        int t = (tid >= off) ? tmp[tid - off] : 0;
        __syncthreads();
        tmp[tid] += t;
        __syncthreads();
    }
    int mystart = estart + tmp[tid] - v;   // exclusive within bucket
    noffs[tid] = mystart;
    ncur[tid]  = 0;
    int node = base + tid;
    if (node < n) {
        offs[node] = mystart;
        hist[node] = v;
        dinv[node] = rsqrtf((float)(v + 1));   // +1 self loop
    }
    __syncthreads();
    for (int i = estart + tid; i < eend; i += 256) {
        unsigned int p = packed[i];
        int d = p & 255u;
        int pos = noffs[d] + atomicAdd(&ncur[d], 1);
        ssrc[pos] = (int)(p >> 8);
    }
}

// ---------------- layer-0 matmul: Hs[n] = dinv[n] * (x[n] @ W) -> bf16 ----------------

__global__ void k_matmul(const float* __restrict__ h, const float* __restrict__ W,
                         const float* __restrict__ dinv, bf16* __restrict__ Hs, int n) {
    int lane = threadIdx.x & 63;
    int wv   = threadIdx.x >> 6;

    float Wreg[64];
#pragma unroll
    for (int k = 0; k < 64; k++) Wreg[k] = W[k * 64 + lane];

    for (int row = blockIdx.x * 4 + wv; row < n; row += gridDim.x * 4) {
        float hval = h[row * 64 + lane];
        float acc = 0.f;
#pragma unroll
        for (int k = 0; k < 64; k++)
            acc = fmaf(__shfl(hval, k, 64), Wreg[k], acc);
        Hs[row * 64 + lane] = __float2bfloat16(dinv[row] * acc);
    }
}

// ------- gather + bias + BN(eval) + relu + JK-pool + fused next-layer matmul -------
// One wave per node, lane = feature (R9-proven layout: index loads are
// wave-uniform -> scalar SMEM, independent of the row-load vmcnt queue).
// 16x unrolled edge loop: 16 independent 128B row loads in flight per wave
// (mean degree 16 -> most nodes complete in one batch). R10's half-wave
// split regressed (lane-dependent index loads joined the vmcnt FIFO).

__global__ void __launch_bounds__(256) k_gather(
    const bf16* __restrict__ Hs, const int* __restrict__ ssrc,
    const int* __restrict__ offs, const int* __restrict__ hist,
    const float* __restrict__ dinv, const float* __restrict__ bias,
    const float* __restrict__ gamma, const float* __restrict__ beta,
    const float* __restrict__ mean, const float* __restrict__ var,
    const int* __restrict__ batch, const float* __restrict__ Wnext,
    bf16* __restrict__ HsNext, float* __restrict__ pooled, int layer, int n)
{
    int node = blockIdx.x * 4 + (threadIdx.x >> 6);
    int lane = threadIdx.x & 63;
    if (node >= n) return;

    int start = __builtin_amdgcn_readfirstlane(offs[node]);
    int cnt   = __builtin_amdgcn_readfirstlane(hist[node]);

    float acc = b2f(Hs[node * 64 + lane]);        // self-loop term (pre-scaled)
    int i = 0;
    for (; i + 15 < cnt; i += 16) {
        int s0  = ssrc[start + i];
        int s1  = ssrc[start + i + 1];
        int s2  = ssrc[start + i + 2];
        int s3  = ssrc[start + i + 3];
        int s4  = ssrc[start + i + 4];
        int s5  = ssrc[start + i + 5];
        int s6  = ssrc[start + i + 6];
        int s7  = ssrc[start + i + 7];
        int s8  = ssrc[start + i + 8];
        int s9  = ssrc[start + i + 9];
        int s10 = ssrc[start + i + 10];
        int s11 = ssrc[start + i + 11];
        int s12 = ssrc[start + i + 12];
        int s13 = ssrc[start + i + 13];
        int s14 = ssrc[start + i + 14];
        int s15 = ssrc[start + i + 15];
        float v0  = b2f(Hs[s0  * 64 + lane]);
        float v1  = b2f(Hs[s1  * 64 + lane]);
        float v2  = b2f(Hs[s2  * 64 + lane]);
        float v3  = b2f(Hs[s3  * 64 + lane]);
        float v4  = b2f(Hs[s4  * 64 + lane]);
        float v5  = b2f(Hs[s5  * 64 + lane]);
        float v6  = b2f(Hs[s6  * 64 + lane]);
        float v7  = b2f(Hs[s7  * 64 + lane]);
        float v8  = b2f(Hs[s8  * 64 + lane]);
        float v9  = b2f(Hs[s9  * 64 + lane]);
        float v10 = b2f(Hs[s10 * 64 + lane]);
        float v11 = b2f(Hs[s11 * 64 + lane]);
        float v12 = b2f(Hs[s12 * 64 + lane]);
        float v13 = b2f(Hs[s13 * 64 + lane]);
        float v14 = b2f(Hs[s14 * 64 + lane]);
        float v15 = b2f(Hs[s15 * 64 + lane]);
        acc += (((v0 + v1) + (v2 + v3)) + ((v4 + v5) + (v6 + v7))) +
               (((v8 + v9) + (v10 + v11)) + ((v12 + v13) + (v14 + v15)));
    }
    for (; i + 7 < cnt; i += 8) {
        int s0 = ssrc[start + i];
        int s1 = ssrc[start + i + 1];
        int s2 = ssrc[start + i + 2];
        int s3 = ssrc[start + i + 3];
        int s4 = ssrc[start + i + 4];
        int s5 = ssrc[start + i + 5];
        int s6 = ssrc[start + i + 6];
        int s7 = ssrc[start + i + 7];
        float v0 = b2f(Hs[s0 * 64 + lane]);
        float v1 = b2f(Hs[s1 * 64 + lane]);
        float v2 = b2f(Hs[s2 * 64 + lane]);
        float v3 = b2f(Hs[s3 * 64 + lane]);
        float v4 = b2f(Hs[s4 * 64 + lane]);
        float v5 = b2f(Hs[s5 * 64 + lane]);
        float v6 = b2f(Hs[s6 * 64 + lane]);
        float v7 = b2f(Hs[s7 * 64 + lane]);
        acc += ((v0 + v1) + (v2 + v3)) + ((v4 + v5) + (v6 + v7));
    }
    for (; i + 3 < cnt; i += 4) {
        int s0 = ssrc[start + i];
        int s1 = ssrc[start + i + 1];
        int s2 = ssrc[start + i + 2];
        int s3 = ssrc[start + i + 3];
        float v0 = b2f(Hs[s0 * 64 + lane]);
        float v1 = b2f(Hs[s1 * 64 + lane]);
        float v2 = b2f(Hs[s2 * 64 + lane]);
        float v3 = b2f(Hs[s3 * 64 + lane]);
        acc += (v0 + v1) + (v2 + v3);
    }
    for (; i < cnt; i++)
        acc += b2f(Hs[ssrc[start + i] * 64 + lane]);

    float dn = dinv[node];
    float val = dn * acc + bias[lane];
    val = (val - mean[lane]) * (gamma[lane] * rsqrtf(var[lane] + BN_EPS)) + beta[lane];
    val = fmaxf(val, 0.f);

    atomicAdd(&pooled[batch[node] * 256 + layer * 64 + lane], val);

    if (Wnext) {   // fused next-layer matmul: HsNext[node] = dinv[node]*(val @ Wnext)
        float a2 = 0.f;
#pragma unroll
        for (int k = 0; k < 64; k++)
            a2 = fmaf(__shfl(val, k, 64), Wnext[k * 64 + lane], a2);
        HsNext[node * 64 + lane] = __float2bfloat16(dn * a2);
    }
}

// ---------------- final MLP: relu(pooled@W1+b1)@W2+b2 -> f32 out ----------------

__global__ void k_mlp(const float* __restrict__ pooled, const float* __restrict__ W1,
                      const float* __restrict__ b1, const float* __restrict__ W2,
                      const float* __restrict__ b2, float* __restrict__ out) {
    __shared__ float p[256];
    __shared__ float t[64];
    int g = blockIdx.x;
    int tid = threadIdx.x;    // 64 threads
    for (int i = tid; i < 256; i += 64) p[i] = pooled[g * 256 + i];
    __syncthreads();
    float acc = b1[tid];
    for (int k = 0; k < 256; k++)
        acc = fmaf(p[k], W1[k * 64 + tid], acc);
    t[tid] = fmaxf(acc, 0.f);
    __syncthreads();
    if (tid < OUT_DIM) {
        float o = b2[tid];
#pragma unroll
        for (int d = 0; d < 64; d++)
            o = fmaf(t[d], W2[d * OUT_DIM + tid], o);
        out[g * OUT_DIM + tid] = o;
    }
}

// ---------------- host launch ----------------

extern "C" void kernel_launch(void* const* d_in, const int* in_sizes, int n_in,
                              void* d_out, int out_size, void* d_ws, size_t ws_size,
                              hipStream_t stream) {
    const float* x          = (const float*)d_in[0];
    const int*   edge_index = (const int*)d_in[1];
    const int*   batch      = (const int*)d_in[2];
    const float* Wl[4] = { (const float*)d_in[4], (const float*)d_in[6],
                           (const float*)d_in[8], (const float*)d_in[10] };
    const float* bl[4] = { (const float*)d_in[5], (const float*)d_in[7],
                           (const float*)d_in[9], (const float*)d_in[11] };
    const float* bn_gamma = (const float*)d_in[12];
    const float* bn_beta  = (const float*)d_in[13];
    const float* bn_mean  = (const float*)d_in[14];
    const float* bn_var   = (const float*)d_in[15];
    const float* lin1_W = (const float*)d_in[16];
    const float* lin1_b = (const float*)d_in[17];
    const float* lin2_W = (const float*)d_in[18];
    const float* lin2_b = (const float*)d_in[19];

    const int* src = edge_index;             // edge_index[0, :]
    const int* dst = edge_index + N_EDGES;   // edge_index[1, :]

    // ---- workspace bump allocator (~41 MB) ----
    char* p = (char*)d_ws;
    auto alloc = [&](size_t bytes) {
        char* r = p;
        p += (bytes + 255) & ~(size_t)255;
        return (void*)r;
    };
    bf16*  HsA    = (bf16*) alloc((size_t)N_NODES * 64 * 2);
    bf16*  HsB    = (bf16*) alloc((size_t)N_NODES * 64 * 2);
    int*   hist   = (int*)  alloc((size_t)N_NODES * 4);
    int*   offs   = (int*)  alloc((size_t)N_NODES * 4);
    float* dinv   = (float*)alloc((size_t)N_NODES * 4);
    int*   ssrc   = (int*)  alloc((size_t)N_EDGES * 4);
    unsigned int* packed = (unsigned int*)alloc((size_t)N_EDGES * 4);
    int*   tileCnt   = (int*)alloc((size_t)NBUCKET * NT * 4);
    int*   bucketTot = (int*)alloc((size_t)NBUCKET * 4);
    float* pooled = (float*)alloc((size_t)N_GRAPHS * 256 * 4);

    hipMemsetAsync(pooled, 0, (size_t)N_GRAPHS * 256 * 4, stream);

    // deterministic bucketed counting sort (no global atomics anywhere)
    k_bucket_count<<<NT, 256, 0, stream>>>(dst, tileCnt, N_EDGES);
    k_tile_scan<<<NBUCKET, 256, 0, stream>>>(tileCnt, bucketTot);
    k_scan_sums<<<1, 512, 0, stream>>>(bucketTot, NBUCKET);       // -> bucket bases
    k_bucket_write<<<NT, 256, 0, stream>>>(src, dst, bucketTot, tileCnt, packed, N_EDGES);
    k_local_sort<<<NBUCKET, 256, 0, stream>>>(packed, bucketTot, ssrc, offs, hist,
                                              dinv, N_NODES, N_EDGES);

    // layer-0 matmul, then 4 fused gather layers (ping-pong Hs buffers)
    k_matmul<<<2048, 256, 0, stream>>>(x, Wl[0], dinv, HsA, N_NODES);

    const int gatherBlocks = (N_NODES + 3) / 4;  // 4 waves/block, 1 node/wave
    bf16* hsIn[4]  = { HsA, HsB, HsA, HsB };
    bf16* hsOut[4] = { HsB, HsA, HsB, (bf16*)nullptr };
    for (int layer = 0; layer < 4; layer++) {
        const float* wn = (layer < 3) ? Wl[layer + 1] : nullptr;
        k_gather<<<gatherBlocks, 256, 0, stream>>>(
            hsIn[layer], ssrc, offs, hist, dinv, bl[layer],
            bn_gamma + layer * 64, bn_beta + layer * 64,
            bn_mean + layer * 64, bn_var + layer * 64,
            batch, wn, hsOut[layer], pooled, layer, N_NODES);
    }

    k_mlp<<<N_GRAPHS, 64, 0, stream>>>(pooled, lin1_W, lin1_b, lin2_W, lin2_b,
                                       (float*)d_out);
}